// Round 4
// baseline (187.708 us; speedup 1.0000x reference)
//
#include <hip/hip_runtime.h>

#define CMIN -1024.0f
#define CMAX 1016.0f
#define SENTINEL 0x13572468u

__device__ __forceinline__ float clampv(float x) {
    return fminf(fmaxf(x, CMIN), CMAX);
}

__device__ __forceinline__ float wave_reduce(float v) {
    #pragma unroll
    for (int off = 32; off > 0; off >>= 1)
        v += __shfl_down(v, off, 64);
    return v;
}

// ---------------------------------------------------------------------------
// Single dispatch, one-shot grid (proven-fast shape), no memset, no atomicsum,
// no grid.sync.
//
//   y-blocks   (0..yblocks-1):      out = clamp(clamp(y)*1.9)
//   c-blocks   (yblocks..+cblocks): out = clamp(clamp(c)*1.9) for all bytes
//     EXCEPT the .x of DC float4s (written by fixup only -> every out byte has
//     exactly one writer; no cross-XCD same-byte hazard). Each c-block
//     publishes {DC-partial, SENTINEL} as ONE relaxed 64-bit agent-scope
//     atomic to ws[cb] -- value is self-contained, so no fence/ordering
//     needed, and poison (0xAAAAAAAA) can't fake the flag -> no memset.
//   fixup      (last 512 c-blocks by index): after finishing their own
//     payload slice, poll the 8192 pairs (batched relaxed atomic sweeps,
//     re-loading only stale entries), reduce both channel sums, then each
//     thread writes one corrected DC: clamp(clamp(c_dc)*1.9 - 0.9*mean).
//     c_dc is re-read from the immutable input (L3-resident). Deadlock-free:
//     512 pollers << ~2048 resident-block capacity, and pollers only wait on
//     blocks that never wait on anything.
// ---------------------------------------------------------------------------
__global__ void __launch_bounds__(256)
fused_all(const float4* __restrict__ y4, const float4* __restrict__ c4,
          const float* __restrict__ cf, float4* __restrict__ out,
          unsigned long long* __restrict__ pairs,
          int ynvec, int yblocks, int cblocks, int dc_per_ch,
          float neg09_inv_count)
{
    __shared__ float sm[8];
    __shared__ float sadj[2];

    const int bid = blockIdx.x;
    const int tid = bid * 256 + threadIdx.x;
    const int lane = threadIdx.x & 63;
    const int wave = threadIdx.x >> 6;

    // ---- y payload ----
    if (bid < yblocks) {
        float4 v = y4[tid];
        v.x = clampv(clampv(v.x) * 1.9f);
        v.y = clampv(clampv(v.y) * 1.9f);
        v.z = clampv(clampv(v.z) * 1.9f);
        v.w = clampv(clampv(v.w) * 1.9f);
        out[tid] = v;
        return;
    }

    // ---- c payload ----
    const int cb = bid - yblocks;            // 0..cblocks-1
    const int ic = tid - ynvec;              // c float4 index
    float4 v = c4[ic];
    const bool isDC = (ic & 15) == 0;        // .x is the DC of its 8x8 block

    float ry = clampv(clampv(v.y) * 1.9f);
    float rz = clampv(clampv(v.z) * 1.9f);
    float rw = clampv(clampv(v.w) * 1.9f);
    if (!isDC) {
        float4 r;
        r.x = clampv(clampv(v.x) * 1.9f);
        r.y = ry; r.z = rz; r.w = rw;
        out[ynvec + ic] = r;
    } else {
        // leave .x for the fixup writer (byte-disjoint stores merge in HW)
        float* p = (float*)&out[ynvec + ic];
        p[1] = ry; p[2] = rz; p[3] = rw;
    }

    // per-block DC partial -> self-contained atomic pair ws[cb]
    float dcv = isDC ? clampv(v.x) : 0.0f;
    float s = wave_reduce(dcv);
    if (lane == 0) sm[wave] = s;
    __syncthreads();
    if (threadIdx.x == 0) {
        float part = sm[0] + sm[1] + sm[2] + sm[3];
        unsigned long long pk =
            ((unsigned long long)SENTINEL << 32) | (unsigned long long)__float_as_uint(part);
        __hip_atomic_store(&pairs[cb], pk, __ATOMIC_RELAXED,
                           __HIP_MEMORY_SCOPE_AGENT);
    }

    // ---- fixup: last 512 c-blocks by index ----
    const int fb = cb - (cblocks - 512);
    if (fb < 0) return;
    __syncthreads();                          // sm reuse barrier

    // poll all 8192 pairs: 32 per thread, batched relaxed sweeps (MLP),
    // re-load only stale entries
    unsigned long long pk[32];
    #pragma unroll
    for (int k = 0; k < 32; ++k)
        pk[k] = __hip_atomic_load(&pairs[threadIdx.x + (k << 8)],
                                  __ATOMIC_RELAXED, __HIP_MEMORY_SCOPE_AGENT);
    for (;;) {
        bool all = true;
        #pragma unroll
        for (int k = 0; k < 32; ++k) {
            if ((unsigned)(pk[k] >> 32) != SENTINEL) {
                all = false;
                pk[k] = __hip_atomic_load(&pairs[threadIdx.x + (k << 8)],
                                          __ATOMIC_RELAXED,
                                          __HIP_MEMORY_SCOPE_AGENT);
            }
        }
        if (all) break;
    }

    // accumulate both channels (pairs 0..4095 = ch0, 4096..8191 = ch1);
    // fixed summation order -> deterministic, identical in all 512 blocks
    float s0 = 0.0f, s1 = 0.0f;
    #pragma unroll
    for (int k = 0; k < 16; ++k) s0 += __uint_as_float((unsigned)pk[k]);
    #pragma unroll
    for (int k = 16; k < 32; ++k) s1 += __uint_as_float((unsigned)pk[k]);
    s0 = wave_reduce(s0);
    s1 = wave_reduce(s1);
    if (lane == 0) { sm[wave] = s0; sm[4 + wave] = s1; }
    __syncthreads();
    if (threadIdx.x == 0) {
        sadj[0] = (sm[0] + sm[1] + sm[2] + sm[3]) * neg09_inv_count;
        sadj[1] = (sm[4] + sm[5] + sm[6] + sm[7]) * neg09_inv_count;
    }
    __syncthreads();

    // one corrected DC per thread: re-read immutable input (L3-resident)
    const int d = fb * 256 + threadIdx.x;     // DC index 0..131071
    const float adj = (d < dc_per_ch) ? sadj[0] : sadj[1];
    const float pre = clampv(cf[(size_t)d * 64]) * 1.9f;
    ((float*)&out[ynvec])[(size_t)d * 64] = clampv(pre + adj);
}

extern "C" void kernel_launch(void* const* d_in, const int* in_sizes, int n_in,
                              void* d_out, int out_size, void* d_ws, size_t ws_size,
                              hipStream_t stream) {
    const float* y = (const float*)d_in[0];
    const float* c = (const float*)d_in[1];
    float* out = (float*)d_out;

    const int yN = in_sizes[0];             // 16777216 floats
    const int cN = in_sizes[1];             // 8388608 floats

    const int ynvec    = yN / 4;            // 4194304 float4
    const int cnvec    = cN / 4;            // 2097152 float4
    const int yblocks  = ynvec / 256;       // 16384
    const int cblocks  = cnvec / 256;       // 8192
    const int dc_per_ch = (cN / 64) / 2;    // 65536
    const float neg09_inv_count = -0.9f / (float)dc_per_ch;

    fused_all<<<yblocks + cblocks, 256, 0, stream>>>(
        (const float4*)y, (const float4*)c, c, (float4*)out,
        (unsigned long long*)d_ws, ynvec, yblocks, cblocks, dc_per_ch,
        neg09_inv_count);
}

// Round 5
// 185.401 us; speedup vs baseline: 1.0124x; 1.0124x over previous
//
#include <hip/hip_runtime.h>

#define CMIN -1024.0f
#define CMAX 1016.0f
#define SENTINEL 0x13572468u

__device__ __forceinline__ float clampv(float x) {
    return fminf(fmaxf(x, CMIN), CMAX);
}

__device__ __forceinline__ float wave_reduce(float v) {
    #pragma unroll
    for (int off = 32; off > 0; off >>= 1)
        v += __shfl_down(v, off, 64);
    return v;
}

// ---------------------------------------------------------------------------
// Single dispatch, one-shot grid + 1 reducer block. No memset, no grid.sync,
// no cooperative launch.
//
// Roles (block-uniform):
//   y-blocks [0, yblocks):            out = clamp(clamp(y)*1.9), full float4.
//   c-blocks [yblocks, yblocks+cb):   out = clamp(clamp(c)*1.9) via ONE
//     predicated float4 store (DC float4s skipped entirely -> fixup owns all
//     16 bytes; every out byte has exactly one writer -> no cross-XCD
//     dual-dirty-line hazard). Block DC partial published as a self-contained
//     {SENTINEL|float} relaxed agent atomic -> no init needed (poison
//     0xAAAAAAAA can't fake SENTINEL), no fences needed.
//   reducer (last block): polls the 8192 pairs (64 KB sweeps from ONE block,
//     s_sleep backoff -- 512x less poll traffic than round 4), reduces both
//     channels in fixed order, publishes 2 self-contained {SENTINEL|adj}
//     words.
//   fixup (last 512 c-blocks, AFTER publishing their own partial): poll just
//     the 2 broadcast words (one line, wave-coalesced), then each thread
//     rebuilds one full DC float4 from the L3-resident input and stores 16 B.
//
// Deadlock-free: pollers (513 blocks) are the last-dispatched; producers
// never wait on anything; resident-block capacity (~2048) >> 513.
// ---------------------------------------------------------------------------
__global__ void __launch_bounds__(256)
fused_all(const float4* __restrict__ y4, const float4* __restrict__ c4,
          float4* __restrict__ out,
          unsigned long long* __restrict__ pairs,   // [8192]
          unsigned long long* __restrict__ bcast,   // [2]
          int ynvec, int yblocks, int cblocks, int c_half_nvec,
          float neg09_inv_count)
{
    __shared__ float sm[8];
    const int bid  = blockIdx.x;
    const int lt   = threadIdx.x;
    const int lane = lt & 63;
    const int wave = lt >> 6;

    // ---------------- y payload ----------------
    if (bid < yblocks) {
        const int i = bid * 256 + lt;
        float4 v = y4[i];
        v.x = clampv(clampv(v.x) * 1.9f);
        v.y = clampv(clampv(v.y) * 1.9f);
        v.z = clampv(clampv(v.z) * 1.9f);
        v.w = clampv(clampv(v.w) * 1.9f);
        out[i] = v;
        return;
    }

    // ---------------- reducer block ----------------
    if (bid >= yblocks + cblocks) {
        // poll all 8192 pairs: 32/thread, re-load only stale, s_sleep backoff
        unsigned long long pk[32];
        #pragma unroll
        for (int k = 0; k < 32; ++k)
            pk[k] = __hip_atomic_load(&pairs[lt + (k << 8)],
                                      __ATOMIC_RELAXED, __HIP_MEMORY_SCOPE_AGENT);
        for (;;) {
            bool all = true;
            #pragma unroll
            for (int k = 0; k < 32; ++k) {
                if ((unsigned)(pk[k] >> 32) != SENTINEL) {
                    all = false;
                    pk[k] = __hip_atomic_load(&pairs[lt + (k << 8)],
                                              __ATOMIC_RELAXED,
                                              __HIP_MEMORY_SCOPE_AGENT);
                }
            }
            if (all) break;
            __builtin_amdgcn_s_sleep(2);
        }
        // fixed-order accumulate: pairs[0..4095]=ch0, [4096..8191]=ch1
        float s0 = 0.0f, s1 = 0.0f;
        #pragma unroll
        for (int k = 0; k < 16; ++k) s0 += __uint_as_float((unsigned)pk[k]);
        #pragma unroll
        for (int k = 16; k < 32; ++k) s1 += __uint_as_float((unsigned)pk[k]);
        s0 = wave_reduce(s0);
        s1 = wave_reduce(s1);
        if (lane == 0) { sm[wave] = s0; sm[4 + wave] = s1; }
        __syncthreads();
        if (lt == 0) {
            float adj0 = (sm[0] + sm[1] + sm[2] + sm[3]) * neg09_inv_count;
            float adj1 = (sm[4] + sm[5] + sm[6] + sm[7]) * neg09_inv_count;
            unsigned long long b0 = ((unsigned long long)SENTINEL << 32) |
                                    (unsigned long long)__float_as_uint(adj0);
            unsigned long long b1 = ((unsigned long long)SENTINEL << 32) |
                                    (unsigned long long)__float_as_uint(adj1);
            __hip_atomic_store(&bcast[0], b0, __ATOMIC_RELAXED,
                               __HIP_MEMORY_SCOPE_AGENT);
            __hip_atomic_store(&bcast[1], b1, __ATOMIC_RELAXED,
                               __HIP_MEMORY_SCOPE_AGENT);
        }
        return;
    }

    // ---------------- c payload ----------------
    const int cb = bid - yblocks;             // 0..cblocks-1
    const int ic = cb * 256 + lt;             // c float4 index
    float4 v = c4[ic];
    const bool isDC = (ic & 15) == 0;         // .x is DC of its 8x8 block

    float4 r;
    r.x = clampv(clampv(v.x) * 1.9f);
    r.y = clampv(clampv(v.y) * 1.9f);
    r.z = clampv(clampv(v.z) * 1.9f);
    r.w = clampv(clampv(v.w) * 1.9f);
    if (!isDC) out[ynvec + ic] = r;           // single predicated 16B store

    // per-block DC partial -> self-contained sentinel pair
    float dcv = isDC ? clampv(v.x) : 0.0f;
    float s = wave_reduce(dcv);
    if (lane == 0) sm[wave] = s;
    __syncthreads();
    if (lt == 0) {
        float part = sm[0] + sm[1] + sm[2] + sm[3];
        unsigned long long pk = ((unsigned long long)SENTINEL << 32) |
                                (unsigned long long)__float_as_uint(part);
        __hip_atomic_store(&pairs[cb], pk, __ATOMIC_RELAXED,
                           __HIP_MEMORY_SCOPE_AGENT);
    }

    // ---------------- fixup role: last 512 c-blocks ----------------
    const int fb = cb - (cblocks - 512);
    if (fb < 0) return;

    // poll ONLY the 2 broadcast words (one line, wave-coalesced)
    unsigned long long b0, b1;
    for (;;) {
        b0 = __hip_atomic_load(&bcast[0], __ATOMIC_RELAXED,
                               __HIP_MEMORY_SCOPE_AGENT);
        b1 = __hip_atomic_load(&bcast[1], __ATOMIC_RELAXED,
                               __HIP_MEMORY_SCOPE_AGENT);
        if ((unsigned)(b0 >> 32) == SENTINEL &&
            (unsigned)(b1 >> 32) == SENTINEL) break;
        __builtin_amdgcn_s_sleep(2);
    }
    const float adj0 = __uint_as_float((unsigned)b0);
    const float adj1 = __uint_as_float((unsigned)b1);

    // rebuild one full DC float4 per thread from the L3-resident input
    const int d   = fb * 256 + lt;            // DC index 0..131071
    const int icd = d << 4;                   // its c float4 index
    float4 v2 = c4[icd];
    float4 r2;
    r2.x = clampv(clampv(v2.x) * 1.9f + ((icd < c_half_nvec) ? adj0 : adj1));
    r2.y = clampv(clampv(v2.y) * 1.9f);
    r2.z = clampv(clampv(v2.z) * 1.9f);
    r2.w = clampv(clampv(v2.w) * 1.9f);
    out[ynvec + icd] = r2;
}

extern "C" void kernel_launch(void* const* d_in, const int* in_sizes, int n_in,
                              void* d_out, int out_size, void* d_ws, size_t ws_size,
                              hipStream_t stream) {
    const float* y = (const float*)d_in[0];
    const float* c = (const float*)d_in[1];
    float* out = (float*)d_out;

    const int yN = in_sizes[0];             // 16777216 floats
    const int cN = in_sizes[1];             // 8388608 floats

    const int ynvec       = yN / 4;         // 4194304 float4
    const int cnvec       = cN / 4;         // 2097152 float4
    const int yblocks     = ynvec / 256;    // 16384
    const int cblocks     = cnvec / 256;    // 8192
    const int c_half_nvec = cnvec / 2;      // 1048576
    const int dc_per_ch   = (cN / 64) / 2;  // 65536
    const float neg09_inv_count = -0.9f / (float)dc_per_ch;

    unsigned long long* pairs = (unsigned long long*)d_ws;   // 8192 pairs
    unsigned long long* bcast = pairs + 8192;                // 2 words

    fused_all<<<yblocks + cblocks + 1, 256, 0, stream>>>(
        (const float4*)y, (const float4*)c, (float4*)out,
        pairs, bcast, ynvec, yblocks, cblocks, c_half_nvec,
        neg09_inv_count);
}

// Round 6
// 181.395 us; speedup vs baseline: 1.0348x; 1.0221x over previous
//
#include <hip/hip_runtime.h>

#define CMIN -1024.0f
#define CMAX 1016.0f

__device__ __forceinline__ float clampv(float x) {
    return fminf(fmaxf(x, CMIN), CMAX);
}

__device__ __forceinline__ float wave_reduce(float v) {
    #pragma unroll
    for (int off = 32; off > 0; off >>= 1)
        v += __shfl_down(v, off, 64);
    return v;
}

__device__ __forceinline__ float4 xform(float4 v) {
    float4 r;
    r.x = clampv(clampv(v.x) * 1.9f);
    r.y = clampv(clampv(v.y) * 1.9f);
    r.z = clampv(clampv(v.z) * 1.9f);
    r.w = clampv(clampv(v.w) * 1.9f);
    return r;
}

// ws layout: ws[0..2047] = per-c-block DC partials (ch0: 0..1023, ch1:
//            1024..2047); ws[2048..133119] = compact pre-adjust DC values.

// ---------------------------------------------------------------------------
// Kernel 1: payload with 4x memory-level parallelism.
//   Block tile = 1024 consecutive float4s; thread t owns tile[t], tile[t+256],
//   tile[t+512], tile[t+768] -- all 4 loads issue before any use (4x in-flight
//   bytes/wave vs the 1-deep round-5 shape; fixes the latency-bound 26%
//   occupancy / 30% HBM diagnosis). 6144 blocks total (4x fewer dispatches).
//   y-blocks [0,4096):  out = clamp(clamp(y)*1.9).
//   c-blocks [4096,6144): same transform; DC slots are exactly the t%16==0
//   threads (tile size is a multiple of 16 -> block-uniform pattern). They
//   additionally stash the pre-adjust value clamp(c)*1.9 into compact dcbuf
//   and contribute clamp(c_dc) to a per-block partial -> ws[cb] (non-atomic,
//   no memset). DC .x placeholders are overwritten by kernel 2 (dispatch
//   boundary orders the two writers).
// ---------------------------------------------------------------------------
__global__ void __launch_bounds__(256)
payload(const float4* __restrict__ y4, const float4* __restrict__ c4,
        float4* __restrict__ out, float* __restrict__ partials,
        float* __restrict__ dcbuf, int yblocks, int ynvec)
{
    const int b = blockIdx.x;
    const int t = threadIdx.x;

    if (b < yblocks) {
        const int base = b * 1024 + t;
        // 4 independent loads, issued back-to-back
        float4 v0 = y4[base];
        float4 v1 = y4[base + 256];
        float4 v2 = y4[base + 512];
        float4 v3 = y4[base + 768];
        out[base]       = xform(v0);
        out[base + 256] = xform(v1);
        out[base + 512] = xform(v2);
        out[base + 768] = xform(v3);
        return;
    }

    // ---- c tile ----
    const int cb   = b - yblocks;           // 0..2047
    const int base = cb * 1024 + t;         // c float4 index of k=0 slot
    float4 v0 = c4[base];
    float4 v1 = c4[base + 256];
    float4 v2 = c4[base + 512];
    float4 v3 = c4[base + 768];

    const bool isDC = (t & 15) == 0;        // base%16==0 <=> t%16==0
    float part = 0.0f;
    if (isDC) {
        // compact stash of pre-adjust values + clamped-DC partial
        const int d0 = base >> 4;           // = cb*64 + (t>>4)
        dcbuf[d0]      = clampv(v0.x) * 1.9f;
        dcbuf[d0 + 16] = clampv(v1.x) * 1.9f;
        dcbuf[d0 + 32] = clampv(v2.x) * 1.9f;
        dcbuf[d0 + 48] = clampv(v3.x) * 1.9f;
        part = clampv(v0.x) + clampv(v1.x) + clampv(v2.x) + clampv(v3.x);
    }

    out[ynvec + base]       = xform(v0);    // DC .x is a placeholder (K2 fixes)
    out[ynvec + base + 256] = xform(v1);
    out[ynvec + base + 512] = xform(v2);
    out[ynvec + base + 768] = xform(v3);

    // block-reduce partial -> partials[cb]
    __shared__ float sm[4];
    float s = wave_reduce(part);
    const int lane = t & 63;
    const int wave = t >> 6;
    if (lane == 0) sm[wave] = s;
    __syncthreads();
    if (t == 0) partials[cb] = sm[0] + sm[1] + sm[2] + sm[3];
}

// ---------------------------------------------------------------------------
// Kernel 2: micro-fixup. 512 blocks x 256 threads, one DC each.
//   Compact dcbuf load issues first; the 2048-partial reduce (8 KB,
//   L2-resident) hides under it. One scattered 4 B store per thread.
// ---------------------------------------------------------------------------
__global__ void __launch_bounds__(256)
dc_fixup(float* __restrict__ outc, const float* __restrict__ partials,
         const float* __restrict__ dcbuf, int dc_per_ch,
         float neg09_inv_count)
{
    const int t = threadIdx.x;
    const int d = blockIdx.x * 256 + t;

    const float pre = dcbuf[d];             // issue payload load first

    float s0 = partials[t] + partials[t + 256] +
               partials[t + 512] + partials[t + 768];
    float s1 = partials[1024 + t] + partials[1280 + t] +
               partials[1536 + t] + partials[1792 + t];
    s0 = wave_reduce(s0);
    s1 = wave_reduce(s1);

    __shared__ float sm[8];
    __shared__ float sadj[2];
    const int lane = t & 63;
    const int wave = t >> 6;
    if (lane == 0) { sm[wave] = s0; sm[4 + wave] = s1; }
    __syncthreads();
    if (t == 0) {
        sadj[0] = (sm[0] + sm[1] + sm[2] + sm[3]) * neg09_inv_count;
        sadj[1] = (sm[4] + sm[5] + sm[6] + sm[7]) * neg09_inv_count;
    }
    __syncthreads();

    const float adj = (d < dc_per_ch) ? sadj[0] : sadj[1];
    outc[(size_t)d * 64] = clampv(pre + adj);
}

extern "C" void kernel_launch(void* const* d_in, const int* in_sizes, int n_in,
                              void* d_out, int out_size, void* d_ws, size_t ws_size,
                              hipStream_t stream) {
    const float* y = (const float*)d_in[0];
    const float* c = (const float*)d_in[1];
    float* out = (float*)d_out;
    float* ws  = (float*)d_ws;

    const int yN = in_sizes[0];             // 16777216 floats
    const int cN = in_sizes[1];             // 8388608 floats

    const int ynvec     = yN / 4;           // 4194304 float4
    const int cnvec     = cN / 4;           // 2097152 float4
    const int yblocks   = ynvec / 1024;     // 4096
    const int cblocks   = cnvec / 1024;     // 2048
    const int dc_count  = cN / 64;          // 131072
    const int dc_per_ch = dc_count / 2;     // 65536
    const float neg09_inv_count = -0.9f / (float)dc_per_ch;

    float* partials = ws;                   // 2048 floats
    float* dcbuf    = ws + 2048;            // 131072 floats

    payload<<<yblocks + cblocks, 256, 0, stream>>>(
        (const float4*)y, (const float4*)c, (float4*)out, partials, dcbuf,
        yblocks, ynvec);

    dc_fixup<<<512, 256, 0, stream>>>(
        out + (size_t)yN, partials, dcbuf, dc_per_ch, neg09_inv_count);
}